// Round 5
// baseline (1329.870 us; speedup 1.0000x reference)
//
#include <hip/hip_runtime.h>

#define EPS 1e-5f

constexpr int Bb  = 128;     // batches
constexpr int Np  = 8192;    // points per batch
constexpr int C1  = 64, C2 = 128, C3 = 256;
constexpr int P   = 64;      // points per chunk (one 16-row M-tile per wave)
constexpr int CHUNKS = 4;    // chunks per block
constexpr int PTS_PER_BLOCK = P * CHUNKS;          // 256
constexpr int BLK_PER_BATCH = Np / PTS_PER_BLOCK;  // 32

typedef __attribute__((ext_vector_type(8))) short short8v;  // 8 bf16 = 4 VGPR
typedef __attribute__((ext_vector_type(4))) float f32x4;    // MFMA acc

__device__ __forceinline__ ushort f2bf(float f) {
  uint x = __float_as_uint(f);
  return (ushort)((x + 0x7fffu + ((x >> 16) & 1u)) >> 16);   // RNE
}

// ---------------------------------------------------------------------------
// prepW: pack W2 [64][128] and W3 [128][256] (f32) into bf16 B-fragments for
// v_mfma_f32_16x16x32_bf16.  Frag order: [tile][kk][lane][i] with
// k = kk*32 + (lane>>4)*8 + i,  n = tile*16 + (lane&15).
// ---------------------------------------------------------------------------
__global__ __launch_bounds__(256) void prepW(const float* __restrict__ W2,
                                             const float* __restrict__ W3,
                                             ushort* __restrict__ W2s,
                                             ushort* __restrict__ W3s) {
  const int idx = blockIdx.x * 256 + threadIdx.x;   // 0..40959
  if (idx < 8192) {
    const int i  = idx & 7;
    const int l  = (idx >> 3) & 63;
    const int kk = (idx >> 9) & 1;
    const int t  = idx >> 10;
    const int k  = kk * 32 + (l >> 4) * 8 + i;
    const int n  = t * 16 + (l & 15);
    W2s[idx] = f2bf(W2[k * C2 + n]);
  } else {
    const int j  = idx - 8192;                      // 0..32767
    const int i  = j & 7;
    const int l  = (j >> 3) & 63;
    const int kk = (j >> 9) & 3;
    const int nt = j >> 11;
    const int k  = kk * 32 + (l >> 4) * 8 + i;
    const int n  = nt * 16 + (l & 15);
    W3s[j] = f2bf(W3[k * C3 + n]);
  }
}

// ---------------------------------------------------------------------------
// Stage A.  Same math as the passing round-4 kernel; register-allocation fixes:
//  * amdgpu_waves_per_eu(2,2): pin allocator target to 2 waves/EU so it uses
//    the 256-VGPR budget instead of spilling acc3/w3f to scratch (round-4
//    counters: 2.9 GB scratch traffic at 128 VGPR).
//  * LN3 stats reduced per-g (8 live stat regs instead of 32).
//  * chunk-invariant b2v/g2v/e2v hoisted out of the chunk loop.
// ---------------------------------------------------------------------------
__global__ __launch_bounds__(256)
__attribute__((amdgpu_waves_per_eu(2, 2)))
void stageA(
    const float* __restrict__ pc,
    const float* __restrict__ W1, const float* __restrict__ b1,
    const float* __restrict__ g1, const float* __restrict__ be1,
    const ushort* __restrict__ W2s, const float* __restrict__ b2,
    const float* __restrict__ g2, const float* __restrict__ be2,
    const ushort* __restrict__ W3s, const float* __restrict__ b3,
    const float* __restrict__ g3, const float* __restrict__ be3,
    float* __restrict__ pooled)      // [B][C3], pre-zeroed, int-bits atomicMax
{
  __shared__ __align__(16) ushort s_h1[4 * 16 * 64];  // 8KB, per-wave [16][64]
  __shared__ __align__(16) ushort s_h2[64 * 128];     // 16KB, [64][128]
  __shared__ float  s_red[4][64][2];                  // per-wave LN3 partials
  __shared__ float2 s_mi[64];                         // per-row (mean, inv)

  const int tid  = threadIdx.x;
  const int lane = tid & 63;
  const int w    = tid >> 6;
  const int lrow = lane & 15;        // A-row / C-D col index
  const int lgrp = lane >> 4;
  const int b    = blockIdx.x >> 5;                  // /32
  const int base_pt = (blockIdx.x & 31) * PTS_PER_BLOCK;

  // --- persistent: W3 B-frags (wave's 4 N-tiles), per-col LN params ---
  short8v w3f[4][4];                  // [t][kk] = 64 VGPR
#pragma unroll
  for (int t = 0; t < 4; ++t)
#pragma unroll
    for (int kk = 0; kk < 4; ++kk)
      w3f[t][kk] = *(const short8v*)(W3s + (size_t)(((w * 4 + t) * 4 + kk) * 64 + lane) * 8);

  float b3c[4], g3c[4], e3c[4];
#pragma unroll
  for (int t = 0; t < 4; ++t) {
    const int col = w * 64 + t * 16 + lrow;
    b3c[t] = b3[col]; g3c[t] = g3[col]; e3c[t] = be3[col];
  }

  float b2v[8], g2v[8], e2v[8];       // chunk-invariant, hoisted
#pragma unroll
  for (int t = 0; t < 8; ++t) {
    const int col = t * 16 + lrow;
    b2v[t] = b2[col]; g2v[t] = g2[col]; e2v[t] = be2[col];
  }

  float runmax[4] = {0.f, 0.f, 0.f, 0.f};

  char* const h1b = (char*)s_h1 + w * 2048;   // wave-private 16x64 bf16 region
  const int sw1 = (lrow & 7) << 4;

  for (int ch = 0; ch < CHUNKS; ++ch) {
    // ================= layer 1: 3 -> 64, fp32 VALU =================
    const float* xp = pc + (size_t)(b * Np + base_pt + ch * P + w * 16 + lrow) * 3;
    const float x0 = xp[0], x1 = xp[1], x2 = xp[2];
    float y[16];
#pragma unroll
    for (int j = 0; j < 16; ++j) {
      const int c = lgrp * 16 + j;
      y[j] = x0 * W1[c] + x1 * W1[C1 + c] + x2 * W1[2 * C1 + c] + b1[c];
    }
    float s1 = 0.f, q1 = 0.f;
#pragma unroll
    for (int j = 0; j < 16; ++j) { s1 += y[j]; q1 += y[j] * y[j]; }
    s1 += __shfl_xor(s1, 16, 64); q1 += __shfl_xor(q1, 16, 64);
    s1 += __shfl_xor(s1, 32, 64); q1 += __shfl_xor(q1, 32, 64);
    const float m1 = s1 * (1.f / 64.f);
    const float i1 = rsqrtf(q1 * (1.f / 64.f) - m1 * m1 + EPS);
    uint pk[8];
#pragma unroll
    for (int j2 = 0; j2 < 8; ++j2) {
      const int c0 = lgrp * 16 + 2 * j2;
      const float h0 = fmaxf((y[2 * j2]     - m1) * i1 * g1[c0]     + be1[c0],     0.f);
      const float h1 = fmaxf((y[2 * j2 + 1] - m1) * i1 * g1[c0 + 1] + be1[c0 + 1], 0.f);
      pk[j2] = (uint)f2bf(h0) | ((uint)f2bf(h1) << 16);
    }
    {
      const int base = lrow * 128 + lgrp * 32;   // bytes; two 16B blocks
      *(uint4*)(h1b + ((base     ) ^ sw1)) = make_uint4(pk[0], pk[1], pk[2], pk[3]);
      *(uint4*)(h1b + ((base + 16) ^ sw1)) = make_uint4(pk[4], pk[5], pk[6], pk[7]);
    }
    // wave-private region: compiler-inserted lgkmcnt orders write->read.

    // ================= layer 2: 64 -> 128, MFMA =================
    short8v a2[2];
#pragma unroll
    for (int kk = 0; kk < 2; ++kk)
      a2[kk] = *(const short8v*)(h1b + ((lrow * 128 + (kk * 64 + lgrp * 16)) ^ sw1));

    f32x4 acc2[8];
#pragma unroll
    for (int t = 0; t < 8; ++t) {
      acc2[t] = (f32x4){0.f, 0.f, 0.f, 0.f};
#pragma unroll
      for (int kk = 0; kk < 2; ++kk) {
        const short8v w2f = *(const short8v*)(W2s + (size_t)((t * 2 + kk) * 64 + lane) * 8);
        acc2[t] = __builtin_amdgcn_mfma_f32_16x16x32_bf16(a2[kk], w2f, acc2[t], 0, 0, 0);
      }
    }

    // LN2 (in-wave): rows w*16 + lgrp*4 + j, cols 16t + lrow
    {
      float s2[4] = {0.f,0.f,0.f,0.f}, q2[4] = {0.f,0.f,0.f,0.f};
#pragma unroll
      for (int t = 0; t < 8; ++t)
#pragma unroll
        for (int j = 0; j < 4; ++j) {
          const float v = acc2[t][j] + b2v[t];
          acc2[t][j] = v;
          s2[j] += v; q2[j] += v * v;
        }
#pragma unroll
      for (int m = 1; m < 16; m <<= 1)
#pragma unroll
        for (int j = 0; j < 4; ++j) {
          s2[j] += __shfl_xor(s2[j], m, 64);
          q2[j] += __shfl_xor(q2[j], m, 64);
        }
#pragma unroll
      for (int j = 0; j < 4; ++j) {
        const float m2 = s2[j] * (1.f / 128.f);
        const float i2 = rsqrtf(q2[j] * (1.f / 128.f) - m2 * m2 + EPS);
        const int row = w * 16 + lgrp * 4 + j;
        const int swr = (row & 7) << 4;
#pragma unroll
        for (int t = 0; t < 8; ++t) {
          const float h = fmaxf((acc2[t][j] - m2) * i2 * g2v[t] + e2v[t], 0.f);
          *(ushort*)((char*)s_h2 + row * 256 + ((t * 32 + lrow * 2) ^ swr)) = f2bf(h);
        }
      }
    }
    __syncthreads();   // B1: h2 visible to all waves

    // ================= layer 3: 128 -> 256, MFMA =================
    f32x4 acc3[4][4];  // [g][t] — 64 VGPR, live through LN apply
#pragma unroll
    for (int g = 0; g < 4; ++g) {
      short8v a3[4];
      const int row = g * 16 + lrow;
      const int rb  = row * 256;
      const int swr = (row & 7) << 4;
#pragma unroll
      for (int kk = 0; kk < 4; ++kk)
        a3[kk] = *(const short8v*)((const char*)s_h2 + rb + ((kk * 64 + lgrp * 16) ^ swr));
#pragma unroll
      for (int t = 0; t < 4; ++t) {
        acc3[g][t] = (f32x4){0.f, 0.f, 0.f, 0.f};
#pragma unroll
        for (int kk = 0; kk < 4; ++kk)
          acc3[g][t] = __builtin_amdgcn_mfma_f32_16x16x32_bf16(a3[kk], w3f[t][kk], acc3[g][t], 0, 0, 0);
      }

      // bias + LN3 stats for THIS g only (8 live stat regs, not 32)
      float sg[4] = {0.f,0.f,0.f,0.f}, qg[4] = {0.f,0.f,0.f,0.f};
#pragma unroll
      for (int t = 0; t < 4; ++t)
#pragma unroll
        for (int j = 0; j < 4; ++j) {
          const float v = acc3[g][t][j] + b3c[t];
          acc3[g][t][j] = v;
          sg[j] += v; qg[j] += v * v;
        }
#pragma unroll
      for (int m = 1; m < 16; m <<= 1)
#pragma unroll
        for (int j = 0; j < 4; ++j) {
          sg[j] += __shfl_xor(sg[j], m, 64);
          qg[j] += __shfl_xor(qg[j], m, 64);
        }
      if (lrow == 0) {
#pragma unroll
        for (int j = 0; j < 4; ++j) {
          const int row2 = g * 16 + lgrp * 4 + j;
          s_red[w][row2][0] = sg[j];
          s_red[w][row2][1] = qg[j];
        }
      }
    }
    __syncthreads();   // B2
    if (tid < 64) {
      const float ss = s_red[0][tid][0] + s_red[1][tid][0] + s_red[2][tid][0] + s_red[3][tid][0];
      const float qq = s_red[0][tid][1] + s_red[1][tid][1] + s_red[2][tid][1] + s_red[3][tid][1];
      const float mean = ss * (1.f / 256.f);
      s_mi[tid] = make_float2(mean, rsqrtf(qq * (1.f / 256.f) - mean * mean + EPS));
    }
    __syncthreads();   // B3

#pragma unroll
    for (int g = 0; g < 4; ++g)
#pragma unroll
      for (int j = 0; j < 4; ++j) {
        const float2 mi = s_mi[g * 16 + lgrp * 4 + j];
#pragma unroll
        for (int t = 0; t < 4; ++t) {
          const float h = fmaxf((acc3[g][t][j] - mi.x) * mi.y * g3c[t] + e3c[t], 0.f);
          runmax[t] = fmaxf(runmax[t], h);
        }
      }
  }

  // ---- col max across lanes sharing lrow, then global atomic ----
#pragma unroll
  for (int t = 0; t < 4; ++t) {
    float v = runmax[t];
    v = fmaxf(v, __shfl_xor(v, 16, 64));
    v = fmaxf(v, __shfl_xor(v, 32, 64));
    if (lane < 16)
      atomicMax((int*)&pooled[b * C3 + w * 64 + t * 16 + lane], __float_as_int(v));
  }
}

// ---------------------------------------------------------------------------
// Stage B: pooled -> LN(pooled@Wp+bp) -> film = pc@Wf+bf -> out = s*img + b
// ---------------------------------------------------------------------------
__global__ __launch_bounds__(256) void stageB(
    const float* __restrict__ pooled,  // [B][256]
    const float* __restrict__ img,     // [B][512]
    const float* __restrict__ Wp, const float* __restrict__ bp,
    const float* __restrict__ gp, const float* __restrict__ bep,
    const float* __restrict__ Wf, const float* __restrict__ bf,
    float* __restrict__ out)           // [B][512]
{
  __shared__ float s_pool[C3];
  __shared__ float s_pc[C3];
  __shared__ float s_red[8];

  const int t = threadIdx.x, b = blockIdx.x;
  const int lane = t & 63, w = t >> 6;

  s_pool[t] = pooled[b * C3 + t];
  __syncthreads();

  float y = bp[t];
  for (int k = 0; k < C3; ++k) y += s_pool[k] * Wp[k * C3 + t];

  float s = y, q = y * y;
  for (int m = 1; m < 64; m <<= 1) { s += __shfl_xor(s, m, 64); q += __shfl_xor(q, m, 64); }
  if (lane == 0) { s_red[w * 2] = s; s_red[w * 2 + 1] = q; }
  __syncthreads();
  s = s_red[0] + s_red[2] + s_red[4] + s_red[6];
  q = s_red[1] + s_red[3] + s_red[5] + s_red[7];
  const float mean = s * (1.f / 256.f);
  const float var  = q * (1.f / 256.f) - mean * mean;
  const float inv  = rsqrtf(var + EPS);
  s_pc[t] = (y - mean) * inv * gp[t] + bep[t];
  __syncthreads();

  float f0 = bf[t], f1 = bf[256 + t], f2 = bf[512 + t], f3 = bf[768 + t];
  for (int k = 0; k < C3; ++k) {
    const float pv = s_pc[k];
    f0 += pv * Wf[k * 1024 + t];
    f1 += pv * Wf[k * 1024 + 256 + t];
    f2 += pv * Wf[k * 1024 + 512 + t];
    f3 += pv * Wf[k * 1024 + 768 + t];
  }
  out[b * 512 + t]       = f0 * img[b * 512 + t]       + f2;
  out[b * 512 + 256 + t] = f1 * img[b * 512 + 256 + t] + f3;
}

extern "C" void kernel_launch(void* const* d_in, const int* in_sizes, int n_in,
                              void* d_out, int out_size, void* d_ws, size_t ws_size,
                              hipStream_t stream) {
  const float* pc  = (const float*)d_in[0];
  const float* img = (const float*)d_in[1];
  const float* W1  = (const float*)d_in[2];
  const float* b1  = (const float*)d_in[3];
  const float* g1  = (const float*)d_in[4];
  const float* be1 = (const float*)d_in[5];
  const float* W2  = (const float*)d_in[6];
  const float* b2  = (const float*)d_in[7];
  const float* g2  = (const float*)d_in[8];
  const float* be2 = (const float*)d_in[9];
  const float* W3  = (const float*)d_in[10];
  const float* b3  = (const float*)d_in[11];
  const float* g3  = (const float*)d_in[12];
  const float* be3 = (const float*)d_in[13];
  const float* Wp  = (const float*)d_in[14];
  const float* bp  = (const float*)d_in[15];
  const float* gp  = (const float*)d_in[16];
  const float* bep = (const float*)d_in[17];
  const float* Wf  = (const float*)d_in[18];
  const float* bf  = (const float*)d_in[19];

  float*  pooled = (float*)d_ws;                                   // 128 KB
  ushort* W2s = (ushort*)((char*)d_ws + Bb * C3 * sizeof(float));  // 16 KB
  ushort* W3s = W2s + 8192;                                        // 64 KB

  hipMemsetAsync(pooled, 0, Bb * C3 * sizeof(float), stream);
  prepW<<<160, 256, 0, stream>>>(W2, W3, W2s, W3s);
  stageA<<<Bb * BLK_PER_BATCH, 256, 0, stream>>>(
      pc, W1, b1, g1, be1, W2s, b2, g2, be2, W3s, b3, g3, be3, pooled);
  stageB<<<Bb, 256, 0, stream>>>(pooled, img, Wp, bp, gp, bep, Wf, bf,
                                 (float*)d_out);
}

// Round 6
// 630.229 us; speedup vs baseline: 2.1101x; 2.1101x over previous
//
#include <hip/hip_runtime.h>

#define EPS 1e-5f

constexpr int Bb  = 128;     // batches
constexpr int Np  = 8192;    // points per batch
constexpr int C1  = 64, C2 = 128, C3 = 256;
constexpr int P   = 64;      // points per chunk (one 16-row M-tile per wave)
constexpr int CHUNKS = 4;    // chunks per block
constexpr int PTS_PER_BLOCK = P * CHUNKS;          // 256
constexpr int BLK_PER_BATCH = Np / PTS_PER_BLOCK;  // 32

typedef __attribute__((ext_vector_type(8))) short short8v;  // 8 bf16 = 4 VGPR
typedef __attribute__((ext_vector_type(4))) float f32x4;    // MFMA acc

__device__ __forceinline__ ushort f2bf(float f) {
  uint x = __float_as_uint(f);
  return (ushort)((x + 0x7fffu + ((x >> 16) & 1u)) >> 16);   // RNE
}

// ---------------------------------------------------------------------------
// prepW: pack W2 [64][128] and W3 [128][256] (f32) into bf16 B-fragments for
// v_mfma_f32_16x16x32_bf16.  Frag order: [tile][kk][lane][i] with
// k = kk*32 + (lane>>4)*8 + i,  n = tile*16 + (lane&15).
// ---------------------------------------------------------------------------
__global__ __launch_bounds__(256) void prepW(const float* __restrict__ W2,
                                             const float* __restrict__ W3,
                                             ushort* __restrict__ W2s,
                                             ushort* __restrict__ W3s) {
  const int idx = blockIdx.x * 256 + threadIdx.x;   // 0..40959
  if (idx < 8192) {
    const int i  = idx & 7;
    const int l  = (idx >> 3) & 63;
    const int kk = (idx >> 9) & 1;
    const int t  = idx >> 10;
    const int k  = kk * 32 + (l >> 4) * 8 + i;
    const int n  = t * 16 + (l & 15);
    W2s[idx] = f2bf(W2[k * C2 + n]);
  } else {
    const int j  = idx - 8192;                      // 0..32767
    const int i  = j & 7;
    const int l  = (j >> 3) & 63;
    const int kk = (j >> 9) & 3;
    const int nt = j >> 11;
    const int k  = kk * 32 + (l >> 4) * 8 + i;
    const int n  = nt * 16 + (l & 15);
    W3s[j] = f2bf(W3[k * C3 + n]);
  }
}

// ---------------------------------------------------------------------------
// Stage A — low-register-pressure restructure (r4/r5 spilled 2.3-2.9 GB at a
// pinned 128-VGPR arch segment):
//  * L3 is TWO-PASS: pass1 computes MFMA groups transiently (4 acc regs) only
//    for LN stats; pass2 recomputes and normalizes. No 64-reg acc3 live range.
//  * LN params streamed from global (L1-hot), not hoisted (saves 36 regs).
//  * W2 fragments staged once in LDS (saves per-chunk L2 streaming).
//  * w3f stays register-resident (64 VGPR) — wave w owns N-quarter w.
// Peak arch-VGPR demand ~105-127 per phase.
// ---------------------------------------------------------------------------
__global__ __launch_bounds__(256) void stageA(
    const float* __restrict__ pc,
    const float* __restrict__ W1, const float* __restrict__ b1,
    const float* __restrict__ g1, const float* __restrict__ be1,
    const ushort* __restrict__ W2s, const float* __restrict__ b2,
    const float* __restrict__ g2, const float* __restrict__ be2,
    const ushort* __restrict__ W3s, const float* __restrict__ b3,
    const float* __restrict__ g3, const float* __restrict__ be3,
    float* __restrict__ pooled)      // [B][C3], pre-zeroed, int-bits atomicMax
{
  __shared__ __align__(16) ushort s_h1[4 * 16 * 64];  // 8KB, per-wave [16][64]
  __shared__ __align__(16) ushort s_h2[64 * 128];     // 16KB, [64][128]
  __shared__ __align__(16) ushort s_w2[16 * 64 * 8];  // 16KB, W2 frags
  __shared__ float  s_red[4][64][2];                  // per-wave LN3 partials
  __shared__ float2 s_mi[64];                         // per-row (mean, inv)

  const int tid  = threadIdx.x;
  const int lane = tid & 63;
  const int w    = tid >> 6;
  const int lrow = lane & 15;        // A-row / C-D col index
  const int lgrp = lane >> 4;
  const int b    = blockIdx.x >> 5;                  // /32
  const int base_pt = (blockIdx.x & 31) * PTS_PER_BLOCK;

  // --- stage W2 fragments into LDS (once per block) ---
#pragma unroll
  for (int q = 0; q < 4; ++q)
    ((uint4*)s_w2)[q * 256 + tid] = ((const uint4*)W2s)[q * 256 + tid];

  // --- persistent: W3 B-frags (wave's 4 N-tiles) = 64 VGPR ---
  short8v w3f[4][4];                  // [t][kk]
#pragma unroll
  for (int t = 0; t < 4; ++t)
#pragma unroll
    for (int kk = 0; kk < 4; ++kk)
      w3f[t][kk] = *(const short8v*)(W3s + (size_t)(((w * 4 + t) * 4 + kk) * 64 + lane) * 8);

  float runmax[4] = {0.f, 0.f, 0.f, 0.f};

  char* const h1b = (char*)s_h1 + w * 2048;   // wave-private 16x64 bf16 region
  const int sw1 = (lrow & 7) << 4;

  __syncthreads();   // s_w2 ready

  for (int ch = 0; ch < CHUNKS; ++ch) {
    // ================= layer 1: 3 -> 64, fp32 VALU =================
    const float* xp = pc + (size_t)(b * Np + base_pt + ch * P + w * 16 + lrow) * 3;
    const float x0 = xp[0], x1 = xp[1], x2 = xp[2];
    float y[16];
#pragma unroll
    for (int j = 0; j < 16; ++j) {
      const int c = lgrp * 16 + j;
      y[j] = x0 * W1[c] + x1 * W1[C1 + c] + x2 * W1[2 * C1 + c] + b1[c];
    }
    float s1 = 0.f, q1 = 0.f;
#pragma unroll
    for (int j = 0; j < 16; ++j) { s1 += y[j]; q1 += y[j] * y[j]; }
    s1 += __shfl_xor(s1, 16, 64); q1 += __shfl_xor(q1, 16, 64);
    s1 += __shfl_xor(s1, 32, 64); q1 += __shfl_xor(q1, 32, 64);
    const float m1 = s1 * (1.f / 64.f);
    const float i1 = rsqrtf(q1 * (1.f / 64.f) - m1 * m1 + EPS);
    {
      uint pk[8];
#pragma unroll
      for (int j2 = 0; j2 < 8; ++j2) {
        const int c0 = lgrp * 16 + 2 * j2;
        const float h0 = fmaxf((y[2 * j2]     - m1) * i1 * g1[c0]     + be1[c0],     0.f);
        const float h1 = fmaxf((y[2 * j2 + 1] - m1) * i1 * g1[c0 + 1] + be1[c0 + 1], 0.f);
        pk[j2] = (uint)f2bf(h0) | ((uint)f2bf(h1) << 16);
      }
      const int base = lrow * 128 + lgrp * 32;   // bytes; two 16B blocks
      *(uint4*)(h1b + ((base     ) ^ sw1)) = make_uint4(pk[0], pk[1], pk[2], pk[3]);
      *(uint4*)(h1b + ((base + 16) ^ sw1)) = make_uint4(pk[4], pk[5], pk[6], pk[7]);
    }
    // wave-private region: compiler-inserted lgkmcnt orders write->read.

    // ================= layer 2: 64 -> 128, MFMA (single pass) ==========
    short8v a2[2];
#pragma unroll
    for (int kk = 0; kk < 2; ++kk)
      a2[kk] = *(const short8v*)(h1b + ((lrow * 128 + (kk * 64 + lgrp * 16)) ^ sw1));

    {
      f32x4 acc2[8];
      float s2[4] = {0.f,0.f,0.f,0.f}, q2[4] = {0.f,0.f,0.f,0.f};
#pragma unroll
      for (int t = 0; t < 8; ++t) {
        acc2[t] = (f32x4){0.f, 0.f, 0.f, 0.f};
#pragma unroll
        for (int kk = 0; kk < 2; ++kk) {
          const short8v w2f = *(const short8v*)((const char*)s_w2 + (((t * 2 + kk) << 6) + lane) * 16);
          acc2[t] = __builtin_amdgcn_mfma_f32_16x16x32_bf16(a2[kk], w2f, acc2[t], 0, 0, 0);
        }
        const float bb = b2[t * 16 + lrow];
#pragma unroll
        for (int j = 0; j < 4; ++j) {
          const float v = acc2[t][j] + bb;
          acc2[t][j] = v;
          s2[j] += v; q2[j] += v * v;
        }
      }
#pragma unroll
      for (int m = 1; m < 16; m <<= 1)
#pragma unroll
        for (int j = 0; j < 4; ++j) {
          s2[j] += __shfl_xor(s2[j], m, 64);
          q2[j] += __shfl_xor(q2[j], m, 64);
        }
      float m2[4], i2[4];
#pragma unroll
      for (int j = 0; j < 4; ++j) {
        m2[j] = s2[j] * (1.f / 128.f);
        i2[j] = rsqrtf(q2[j] * (1.f / 128.f) - m2[j] * m2[j] + EPS);
      }
#pragma unroll
      for (int t = 0; t < 8; ++t) {
        const int col = t * 16 + lrow;
        const float gg = g2[col], ee = be2[col];
#pragma unroll
        for (int j = 0; j < 4; ++j) {
          const float h = fmaxf((acc2[t][j] - m2[j]) * i2[j] * gg + ee, 0.f);
          const int row = w * 16 + lgrp * 4 + j;
          *(ushort*)((char*)s_h2 + row * 256 + ((t * 32 + lrow * 2) ^ ((row & 7) << 4))) = f2bf(h);
        }
      }
    }
    __syncthreads();   // B1: h2 visible to all waves

    // ====== layer 3 pass 1: MFMA for LN stats only (transient acc) ======
#pragma unroll
    for (int g = 0; g < 4; ++g) {
      short8v a3[4];
      const int row = g * 16 + lrow;
      const int rb  = row * 256;
      const int swr = (row & 7) << 4;
#pragma unroll
      for (int kk = 0; kk < 4; ++kk)
        a3[kk] = *(const short8v*)((const char*)s_h2 + rb + ((kk * 64 + lgrp * 16) ^ swr));

      float sg[4] = {0.f,0.f,0.f,0.f}, qg[4] = {0.f,0.f,0.f,0.f};
#pragma unroll
      for (int t = 0; t < 4; ++t) {
        f32x4 acc = (f32x4){0.f, 0.f, 0.f, 0.f};
#pragma unroll
        for (int kk = 0; kk < 4; ++kk)
          acc = __builtin_amdgcn_mfma_f32_16x16x32_bf16(a3[kk], w3f[t][kk], acc, 0, 0, 0);
        const float bb = b3[w * 64 + t * 16 + lrow];
#pragma unroll
        for (int j = 0; j < 4; ++j) {
          const float v = acc[j] + bb;
          sg[j] += v; qg[j] += v * v;
        }
      }
#pragma unroll
      for (int m = 1; m < 16; m <<= 1)
#pragma unroll
        for (int j = 0; j < 4; ++j) {
          sg[j] += __shfl_xor(sg[j], m, 64);
          qg[j] += __shfl_xor(qg[j], m, 64);
        }
      if (lrow == 0) {
#pragma unroll
        for (int j = 0; j < 4; ++j) {
          const int row2 = g * 16 + lgrp * 4 + j;
          s_red[w][row2][0] = sg[j];
          s_red[w][row2][1] = qg[j];
        }
      }
    }
    __syncthreads();   // B2
    if (tid < 64) {
      const float ss = s_red[0][tid][0] + s_red[1][tid][0] + s_red[2][tid][0] + s_red[3][tid][0];
      const float qq = s_red[0][tid][1] + s_red[1][tid][1] + s_red[2][tid][1] + s_red[3][tid][1];
      const float mean = ss * (1.f / 256.f);
      s_mi[tid] = make_float2(mean, rsqrtf(qq * (1.f / 256.f) - mean * mean + EPS));
    }
    __syncthreads();   // B3

    // ====== layer 3 pass 2: recompute MFMA, normalize, running max ======
#pragma unroll
    for (int g = 0; g < 4; ++g) {
      short8v a3[4];
      const int row = g * 16 + lrow;
      const int rb  = row * 256;
      const int swr = (row & 7) << 4;
#pragma unroll
      for (int kk = 0; kk < 4; ++kk)
        a3[kk] = *(const short8v*)((const char*)s_h2 + rb + ((kk * 64 + lgrp * 16) ^ swr));

#pragma unroll
      for (int t = 0; t < 4; ++t) {
        f32x4 acc = (f32x4){0.f, 0.f, 0.f, 0.f};
#pragma unroll
        for (int kk = 0; kk < 4; ++kk)
          acc = __builtin_amdgcn_mfma_f32_16x16x32_bf16(a3[kk], w3f[t][kk], acc, 0, 0, 0);
        const int col = w * 64 + t * 16 + lrow;
        const float bb = b3[col], gg = g3[col], ee = be3[col];
        float mx = runmax[t];
#pragma unroll
        for (int j = 0; j < 4; ++j) {
          const float2 mi = s_mi[g * 16 + lgrp * 4 + j];
          const float h = fmaxf((acc[j] + bb - mi.x) * mi.y * gg + ee, 0.f);
          mx = fmaxf(mx, h);
        }
        runmax[t] = mx;
      }
    }
    __syncthreads();   // B4: protect h2/s_red/s_mi for next chunk
  }

  // ---- col max across lanes sharing lrow, then global atomic ----
#pragma unroll
  for (int t = 0; t < 4; ++t) {
    float v = runmax[t];
    v = fmaxf(v, __shfl_xor(v, 16, 64));
    v = fmaxf(v, __shfl_xor(v, 32, 64));
    if (lane < 16)
      atomicMax((int*)&pooled[b * C3 + w * 64 + t * 16 + lane], __float_as_int(v));
  }
}

// ---------------------------------------------------------------------------
// Stage B: pooled -> LN(pooled@Wp+bp) -> film = pc@Wf+bf -> out = s*img + b
// ---------------------------------------------------------------------------
__global__ __launch_bounds__(256) void stageB(
    const float* __restrict__ pooled,  // [B][256]
    const float* __restrict__ img,     // [B][512]
    const float* __restrict__ Wp, const float* __restrict__ bp,
    const float* __restrict__ gp, const float* __restrict__ bep,
    const float* __restrict__ Wf, const float* __restrict__ bf,
    float* __restrict__ out)           // [B][512]
{
  __shared__ float s_pool[C3];
  __shared__ float s_pc[C3];
  __shared__ float s_red[8];

  const int t = threadIdx.x, b = blockIdx.x;
  const int lane = t & 63, w = t >> 6;

  s_pool[t] = pooled[b * C3 + t];
  __syncthreads();

  float y = bp[t];
  for (int k = 0; k < C3; ++k) y += s_pool[k] * Wp[k * C3 + t];

  float s = y, q = y * y;
  for (int m = 1; m < 64; m <<= 1) { s += __shfl_xor(s, m, 64); q += __shfl_xor(q, m, 64); }
  if (lane == 0) { s_red[w * 2] = s; s_red[w * 2 + 1] = q; }
  __syncthreads();
  s = s_red[0] + s_red[2] + s_red[4] + s_red[6];
  q = s_red[1] + s_red[3] + s_red[5] + s_red[7];
  const float mean = s * (1.f / 256.f);
  const float var  = q * (1.f / 256.f) - mean * mean;
  const float inv  = rsqrtf(var + EPS);
  s_pc[t] = (y - mean) * inv * gp[t] + bep[t];
  __syncthreads();

  float f0 = bf[t], f1 = bf[256 + t], f2 = bf[512 + t], f3 = bf[768 + t];
  for (int k = 0; k < C3; ++k) {
    const float pv = s_pc[k];
    f0 += pv * Wf[k * 1024 + t];
    f1 += pv * Wf[k * 1024 + 256 + t];
    f2 += pv * Wf[k * 1024 + 512 + t];
    f3 += pv * Wf[k * 1024 + 768 + t];
  }
  out[b * 512 + t]       = f0 * img[b * 512 + t]       + f2;
  out[b * 512 + 256 + t] = f1 * img[b * 512 + 256 + t] + f3;
}

extern "C" void kernel_launch(void* const* d_in, const int* in_sizes, int n_in,
                              void* d_out, int out_size, void* d_ws, size_t ws_size,
                              hipStream_t stream) {
  const float* pc  = (const float*)d_in[0];
  const float* img = (const float*)d_in[1];
  const float* W1  = (const float*)d_in[2];
  const float* b1  = (const float*)d_in[3];
  const float* g1  = (const float*)d_in[4];
  const float* be1 = (const float*)d_in[5];
  const float* W2  = (const float*)d_in[6];
  const float* b2  = (const float*)d_in[7];
  const float* g2  = (const float*)d_in[8];
  const float* be2 = (const float*)d_in[9];
  const float* W3  = (const float*)d_in[10];
  const float* b3  = (const float*)d_in[11];
  const float* g3  = (const float*)d_in[12];
  const float* be3 = (const float*)d_in[13];
  const float* Wp  = (const float*)d_in[14];
  const float* bp  = (const float*)d_in[15];
  const float* gp  = (const float*)d_in[16];
  const float* bep = (const float*)d_in[17];
  const float* Wf  = (const float*)d_in[18];
  const float* bf  = (const float*)d_in[19];

  float*  pooled = (float*)d_ws;                                   // 128 KB
  ushort* W2s = (ushort*)((char*)d_ws + Bb * C3 * sizeof(float));  // 16 KB
  ushort* W3s = W2s + 8192;                                        // 64 KB

  hipMemsetAsync(pooled, 0, Bb * C3 * sizeof(float), stream);
  prepW<<<160, 256, 0, stream>>>(W2, W3, W2s, W3s);
  stageA<<<Bb * BLK_PER_BATCH, 256, 0, stream>>>(
      pc, W1, b1, g1, be1, W2s, b2, g2, be2, W3s, b3, g3, be3, pooled);
  stageB<<<Bb, 256, 0, stream>>>(pooled, img, Wp, bp, gp, bep, Wf, bf,
                                 (float*)d_out);
}